// Round 9
// baseline (143.060 us; speedup 1.0000x reference)
//
#include <hip/hip_runtime.h>
#include <hip/hip_bf16.h>
#include <math.h>

// ---------------- workspace layout (float offsets) ----------------
// proj  [2][8][8][1024]            @ 0        (131072)  (dead after conv;
//        reused: sqw @ 0 (65536), czw @ 65536 (65536) by attnw/attnc)
// conv  [2][4][8][8][1024]         @ 131072   (524288)
// psum  [64][32]                   @ 655360   (2048)
// psumsq[64][32]                   @ 657408   (2048)
// Qt    [64][1024]                 @ 659456   (65536)
// Kt    [64][1024]                 @ 724992   (65536)
namespace {
constexpr int PROJ_OFF = 0;
constexpr int CONV_OFF = 131072;
constexpr int PS_OFF   = 655360;
constexpr int PSS_OFF  = 657408;
constexpr int QT_OFF   = 659456;
constexpr int KT_OFF   = 724992;
constexpr int SQ_OFF   = 0;      // aliases dead proj region
constexpr int CZ_OFF   = 65536;  // aliases dead proj region

typedef short bf16x8 __attribute__((ext_vector_type(8)));
typedef float f32x4 __attribute__((ext_vector_type(4)));

union BF8 {
  bf16x8 v;
  short s[8];
};

// LDS-only barrier: skips the vmcnt(0) drain of __syncthreads (dbuf needs
// only LDS visibility). sched_barrier fences per rule #18.
__device__ inline void lgkm_barrier() {
  __builtin_amdgcn_sched_barrier(0);
  asm volatile("s_waitcnt lgkmcnt(0)" ::: "memory");
  __builtin_amdgcn_s_barrier();
  __builtin_amdgcn_sched_barrier(0);
}

// ---------------- kernel 1: projection q/k = X . W_pq (1 row/thread) -------
__global__ __launch_bounds__(256) void proj_kernel(
    const float* __restrict__ Q, const float* __restrict__ K,
    const float* __restrict__ Wpq, float* __restrict__ proj) {
  __shared__ float wsh[64];
  const int tid = threadIdx.x;
  if (tid < 64) wsh[tid] = Wpq[tid];
  __syncthreads();
  const int row = blockIdx.x * 256 + tid;  // 0..131071
  const float* src = (row < 65536) ? (Q + (size_t)row * 64)
                                   : (K + (size_t)(row - 65536) * 64);
  float acc = 0.f;
#pragma unroll
  for (int j = 0; j < 16; ++j) {
    const float4 v = *(const float4*)(src + j * 4);
    acc = fmaf(v.x, wsh[j * 4 + 0], acc);
    acc = fmaf(v.y, wsh[j * 4 + 1], acc);
    acc = fmaf(v.z, wsh[j * 4 + 2], acc);
    acc = fmaf(v.w, wsh[j * 4 + 3], acc);
  }
  proj[row] = acc;
}

// ---------------- kernel 2: conv1d + per-block BN partial sums --------------
template <int F>
__device__ void conv_body(const float* __restrict__ xs,
                          const float* __restrict__ wsm,
                          const float* __restrict__ bsm,
                          float* __restrict__ outp, int tid, int lq,
                          float accs[8]) {
  constexpr int pad = (F - 1) / 2;
#pragma unroll
  for (int j = 0; j < 8; ++j) {
    float acc = bsm[j];
#pragma unroll
    for (int c = 0; c < 8; ++c) {
      const float* xrow = &xs[c * 264 + tid + 4 - pad];
      const float* wrow = &wsm[(j * 8 + c) * F];
#pragma unroll
      for (int f = 0; f < F; ++f) acc = fmaf(xrow[f], wrow[f], acc);
    }
    outp[j * 1024 + lq * 256 + tid] = acc;
    accs[j] = acc;
  }
}

__global__ __launch_bounds__(256) void conv_kernel(
    const float* __restrict__ proj,
    const float* __restrict__ wq0, const float* __restrict__ bq0,
    const float* __restrict__ wq1, const float* __restrict__ bq1,
    const float* __restrict__ wq2, const float* __restrict__ bq2,
    const float* __restrict__ wq3, const float* __restrict__ bq3,
    const float* __restrict__ wk0, const float* __restrict__ bk0,
    const float* __restrict__ wk1, const float* __restrict__ bk1,
    const float* __restrict__ wk2, const float* __restrict__ bk2,
    const float* __restrict__ wk3, const float* __restrict__ bk3,
    float* __restrict__ conv, float* __restrict__ psum,
    float* __restrict__ psumsq) {
  __shared__ float xs[8 * 264];  // halo of 4 each side
  __shared__ float wsm[8 * 8 * 9];
  __shared__ float bsm[8];
  __shared__ float redS[8][4], redSS[8][4];
  const int tid = threadIdx.x;
  const int blk = blockIdx.x;  // 256 blocks: (path, filt, batch, lq)
  const int path = blk >> 7, fi = (blk >> 5) & 3, bb = (blk >> 2) & 7;
  const int lq = blk & 3;
  const int F = (0x9731 >> (fi * 4)) & 0xF;  // 1,3,7,9
  const float* wp;
  const float* bp;
  if (path == 0) {
    wp = fi == 0 ? wq0 : fi == 1 ? wq1 : fi == 2 ? wq2 : wq3;
    bp = fi == 0 ? bq0 : fi == 1 ? bq1 : fi == 2 ? bq2 : bq3;
  } else {
    wp = fi == 0 ? wk0 : fi == 1 ? wk1 : fi == 2 ? wk2 : wk3;
    bp = fi == 0 ? bk0 : fi == 1 ? bk1 : fi == 2 ? bk2 : bk3;
  }
  const float* pb = proj + path * 65536 + bb * 8192;
  for (int e = tid; e < 8 * 264; e += 256) {
    const int c = e / 264, pos = e - c * 264;
    const int gl = lq * 256 + pos - 4;
    xs[e] = (gl >= 0 && gl < 1024) ? pb[c * 1024 + gl] : 0.f;
  }
  for (int e = tid; e < 64 * F; e += 256) wsm[e] = wp[e];
  if (tid < 8) bsm[tid] = bp[tid];
  __syncthreads();
  float* outp = conv + ((size_t)(path * 4 + fi) * 8 + bb) * 8192;
  float accs[8];
  if (fi == 0)
    conv_body<1>(xs, wsm, bsm, outp, tid, lq, accs);
  else if (fi == 1)
    conv_body<3>(xs, wsm, bsm, outp, tid, lq, accs);
  else if (fi == 2)
    conv_body<7>(xs, wsm, bsm, outp, tid, lq, accs);
  else
    conv_body<9>(xs, wsm, bsm, outp, tid, lq, accs);
  // block reduction of per-channel sum / sumsq (deterministic, no atomics)
  const int lane = tid & 63, wv = tid >> 6;
#pragma unroll
  for (int j = 0; j < 8; ++j) {
    float sv = accs[j], qv = accs[j] * accs[j];
#pragma unroll
    for (int mm = 32; mm >= 1; mm >>= 1) {
      sv += __shfl_xor(sv, mm, 64);
      qv += __shfl_xor(qv, mm, 64);
    }
    if (lane == 0) {
      redS[j][wv] = sv;
      redSS[j][wv] = qv;
    }
  }
  __syncthreads();
  if (tid < 16) {
    const int j = tid & 7;
    const bool wantss = tid >= 8;
    const float* rr = wantss ? &redSS[j][0] : &redS[j][0];
    const float tot = rr[0] + rr[1] + rr[2] + rr[3];
    float* dst = wantss ? psumsq : psum;
    dst[((path * 4 + fi) * 8 + j) * 32 + bb * 4 + lq] = tot;
  }
}

__device__ inline float bn_elu(float v, float mean, float rstd, float g,
                               float be) {
  const float x = (v - mean) * rstd * g + be;
  return x > 0.f ? x : expm1f(x);
}

// ============ register/shuffle bitonic sort machinery ============
__device__ inline void cswap(float& a, float& b, bool up) {
  const float mx = fmaxf(a, b), mn = fminf(a, b);
  a = up ? mx : mn;
  b = up ? mn : mx;
}

__device__ inline void shfl_pass(float v[4], int t, int m, bool up) {
  const bool keepmax = (up == ((t & m) == 0));
#pragma unroll
  for (int e = 0; e < 4; ++e) {
    const float p = __shfl_xor(v[e], m, 64);
    v[e] = keepmax ? fmaxf(v[e], p) : fminf(v[e], p);
  }
}

__device__ inline void lds_pass(float v[4], float* s, int t, int jq, bool up) {
  *(float4*)&s[4 * t] = make_float4(v[0], v[1], v[2], v[3]);
  __syncthreads();
  const int pt = t ^ jq;
  const bool keepmax = (up == ((t & jq) == 0));
  const float4 p = *(const float4*)&s[4 * pt];
  v[0] = keepmax ? fmaxf(v[0], p.x) : fminf(v[0], p.x);
  v[1] = keepmax ? fmaxf(v[1], p.y) : fminf(v[1], p.y);
  v[2] = keepmax ? fmaxf(v[2], p.z) : fminf(v[2], p.z);
  v[3] = keepmax ? fmaxf(v[3], p.w) : fminf(v[3], p.w);
  __syncthreads();
}

__device__ inline void reg_tail(float v[4], int t, bool up) {
#pragma unroll
  for (int m = 32; m >= 1; m >>= 1) shfl_pass(v, t, m, up);
  cswap(v[0], v[2], up);
  cswap(v[1], v[3], up);
  cswap(v[0], v[1], up);
  cswap(v[2], v[3], up);
}

__device__ inline void sort1024(float v[4], float* s, int t) {
  cswap(v[0], v[1], true);
  cswap(v[2], v[3], false);
#pragma unroll
  for (int k = 4; k <= 256; k <<= 1) {
    const bool up = ((t & (k >> 2)) == 0);
    for (int m = k >> 3; m >= 1; m >>= 1) shfl_pass(v, t, m, up);
    cswap(v[0], v[2], up);
    cswap(v[1], v[3], up);
    cswap(v[0], v[1], up);
    cswap(v[2], v[3], up);
  }
  {
    const bool up = ((t & 128) == 0);
    lds_pass(v, s, t, 64, up);
    reg_tail(v, t, up);
  }
  lds_pass(v, s, t, 128, true);
  lds_pass(v, s, t, 64, true);
  reg_tail(v, t, true);
}

__device__ inline void bmerge1024(float v[4], float* s, int t) {
  lds_pass(v, s, t, 128, true);
  lds_pass(v, s, t, 64, true);
  reg_tail(v, t, true);
}

// ---------------- kernel 3: fused stats-finalize + sorts + merge ------------
__global__ __launch_bounds__(256) void sortmerge_kernel(
    const float* __restrict__ conv, const float* __restrict__ psum,
    const float* __restrict__ psumsq, const float* __restrict__ bng,
    const float* __restrict__ bnb, float* __restrict__ Qt,
    float* __restrict__ Kt) {
  __shared__ float s[1024];
  __shared__ float sred[8];
  __shared__ float cm[4], cr[4];
  const int t = threadIdx.x, blk = blockIdx.x;
  const bool isQ = blk < 64;
  const int row = isQ ? blk : blk - 64;
  const int hp = row & 7;
  const int fi = row >> 4;
  const int bb = ((row >> 3) & 1) * 4 + (hp >> 1);
  const int chbase = (isQ ? 0 : 32) + fi * 8 + (hp & 1) * 4;
  if (t < 8) {
    const float* src = (t < 4) ? psum : psumsq;
    const int ch = chbase + (t & 3);
    float a = 0.f;
    for (int i = 0; i < 32; ++i) a += src[ch * 32 + i];
    sred[t] = a;
  }
  __syncthreads();
  if (t < 4) {
    const float mean = sred[t] * (1.f / 8192.f);
    const float var = sred[4 + t] * (1.f / 8192.f) - mean * mean;
    cm[t] = mean;
    cr[t] = rsqrtf(fmaxf(var, 0.f) + 1e-5f);
  }
  __syncthreads();
  if (isQ) {
    const float* base = conv + (size_t)(fi * 8 + bb) * 8192;
    float c0[4], c1[4], c2[4], c3[4];
#pragma unroll
    for (int jc = 0; jc < 4; ++jc) {
      float* v = jc == 0 ? c0 : jc == 1 ? c1 : jc == 2 ? c2 : c3;
      const int hh = (hp & 1) * 4 + jc;
      const float mean = cm[jc], rstd = cr[jc];
      const float g = bng[hh], be = bnb[hh];
      const float4 x = *(const float4*)&base[hh * 1024 + 4 * t];
      v[0] = bn_elu(x.x, mean, rstd, g, be);
      v[1] = bn_elu(x.y, mean, rstd, g, be);
      v[2] = bn_elu(x.z, mean, rstd, g, be);
      v[3] = bn_elu(x.w, mean, rstd, g, be);
      sort1024(v, s, t);
    }
    float a[4], b[4];
    *(float4*)&s[4 * t] = make_float4(c1[0], c1[1], c1[2], c1[3]);
    __syncthreads();
#pragma unroll
    for (int e = 0; e < 4; ++e) a[e] = fmaxf(c0[e], s[1023 - 4 * t - e]);
    __syncthreads();
    bmerge1024(a, s, t);
    *(float4*)&s[4 * t] = make_float4(c3[0], c3[1], c3[2], c3[3]);
    __syncthreads();
#pragma unroll
    for (int e = 0; e < 4; ++e) b[e] = fmaxf(c2[e], s[1023 - 4 * t - e]);
    __syncthreads();
    bmerge1024(b, s, t);
    *(float4*)&s[4 * t] = make_float4(b[0], b[1], b[2], b[3]);
    __syncthreads();
#pragma unroll
    for (int e = 0; e < 4; ++e) a[e] = fmaxf(a[e], s[1023 - 4 * t - e]);
    __syncthreads();
    bmerge1024(a, s, t);
    *(float4*)&Qt[(size_t)row * 1024 + 4 * t] =
        make_float4(a[0], a[1], a[2], a[3]);
  } else {
    float v[4];
    float sum0 = 0.f, sum1 = 0.f, sum2 = 0.f, sum3 = 0.f;
#pragma unroll
    for (int j = 0; j < 4; ++j) {
      const int hh = (hp & 1) * 4 + j;
      const float mean = cm[j], rstd = cr[j];
      const float g = bng[hh], be = bnb[hh];
      const float4 x = *(const float4*)&conv[(size_t)(4 + fi) * 64 * 1024 +
                                             (size_t)bb * 8192 + hh * 1024 +
                                             4 * t];
      sum0 += bn_elu(x.x, mean, rstd, g, be);
      sum1 += bn_elu(x.y, mean, rstd, g, be);
      sum2 += bn_elu(x.z, mean, rstd, g, be);
      sum3 += bn_elu(x.w, mean, rstd, g, be);
    }
    v[0] = sum0 * 0.25f;
    v[1] = sum1 * 0.25f;
    v[2] = sum2 * 0.25f;
    v[3] = sum3 * 0.25f;
    sort1024(v, s, t);
    *(float4*)&Kt[(size_t)row * 1024 + 4 * t] =
        make_float4(v[0], v[1], v[2], v[3]);
  }
}

// ---------------- kernel 4a: softmax + attn WRITE only ----------------------
// grid 2048 = 64 bh x 32 q-tiles of 32 rows; 4 waves; wave handles 8 rows.
// Per row: 16 exps -> wave-reduce z -> scale by 1/z (reuse e's) -> 4
// perfectly-coalesced float4 stores (1024 B per instruction). Also saves
// s_q and c_q = -m - ln z into ws (dead proj region) for the ctx kernel.
__global__ __launch_bounds__(256) void attnw_kernel(
    const float* __restrict__ Qt, const float* __restrict__ Kt,
    const float* __restrict__ Wbq, const float* __restrict__ Wbk,
    float* __restrict__ attn, float* __restrict__ sqw,
    float* __restrict__ czw) {
  __shared__ float Kts[1024];
  const int tid = threadIdx.x;
  const int b = blockIdx.x;
  // XCD swizzle: all 32 q-tiles of one bh on one XCD (2048 % 8 == 0).
  const int bh = ((b & 7) << 3) | ((b >> 3) & 7);
  const int qt = b >> 6;  // 0..31
  const int qbase = qt * 32;
  const int wv = tid >> 6, l = tid & 63;
  float cval;
  {
    float d = Wbq[l] * Wbk[l];
#pragma unroll
    for (int mm = 32; mm >= 1; mm >>= 1) d += __shfl_xor(d, mm, 64);
    cval = d * 0.125f;  // / sqrt(64)
  }
  const float* Ktg = Kt + (size_t)bh * 1024;
  for (int t = tid; t < 1024; t += 256) Kts[t] = Ktg[t];
  const float kHi = Ktg[0], kLo = Ktg[1023];  // sorted descending
  __syncthreads();
  float* arow = attn + ((size_t)bh << 20) + (size_t)qbase * 1024;
  const float* Qrow = Qt + (size_t)bh * 1024 + qbase;
#pragma unroll 2
  for (int r = 0; r < 8; ++r) {
    const int q = wv * 8 + r;  // 0..31 within tile
    const float s = cval * Qrow[q];
    const float m = fmaxf(s * kHi, s * kLo);
    float e[16];
    float z = 0.f;
#pragma unroll
    for (int j = 0; j < 4; ++j) {
      const float4 kv = *(const float4*)&Kts[j * 256 + l * 4];
      e[j * 4 + 0] = __expf(fmaf(s, kv.x, -m));
      e[j * 4 + 1] = __expf(fmaf(s, kv.y, -m));
      e[j * 4 + 2] = __expf(fmaf(s, kv.z, -m));
      e[j * 4 + 3] = __expf(fmaf(s, kv.w, -m));
      z += (e[j * 4 + 0] + e[j * 4 + 1]) + (e[j * 4 + 2] + e[j * 4 + 3]);
    }
#pragma unroll
    for (int mm = 32; mm >= 1; mm >>= 1) z += __shfl_xor(z, mm, 64);
    const float rz = 1.f / z;
    if (l == 0) {
      sqw[(size_t)bh * 1024 + qbase + q] = s;
      czw[(size_t)bh * 1024 + qbase + q] = -m - __logf(z);
    }
    float* ag = arow + (size_t)q * 1024;
#pragma unroll
    for (int j = 0; j < 4; ++j)
      *(float4*)&ag[j * 256 + l * 4] =
          make_float4(e[j * 4 + 0] * rz, e[j * 4 + 1] * rz, e[j * 4 + 2] * rz,
                      e[j * 4 + 3] * rz);
  }
}

// ---------------- kernel 4b: ctx via MFMA PV (E recomputed in-register) -----
// grid 1024 = 64 bh x 16 q-tiles of 64 rows; 4 waves; 4 blocks/CU.
// Same PV structure as R6 but: no Z-pass (reads sq/cz from ws), no attn
// stores. Lane l of wave wv owns q = wv*16 + (l&15), k = kc+ks*32+8*(l>>4)+j
// (the mfma_f32_16x16x32_bf16 A map); V double-buffered in LDS as bf16
// hi/lo B-frags.
__global__ __launch_bounds__(256, 4) void attnc_kernel(
    const float* __restrict__ V, const float* __restrict__ Kt,
    const float* __restrict__ sqw, const float* __restrict__ czw,
    float* __restrict__ ctx) {
  __shared__ float Kts[1024];
  __shared__ float sq[64], cz[64];
  __shared__ short Vhi[2][8 * 64 * 8];  // [buf][ko][d][8k] bf16
  __shared__ short Vlo[2][8 * 64 * 8];
  const int tid = threadIdx.x;
  const int b = blockIdx.x;
  // XCD swizzle: all 16 q-tiles of one bh on one XCD (1024 % 8 == 0).
  const int bh = ((b & 7) << 3) | ((b >> 3) & 7);
  const int qt = b >> 6;  // 0..15
  const int qbase = qt * 64;
  const float* Ktg = Kt + (size_t)bh * 1024;
  for (int t = tid; t < 1024; t += 256) Kts[t] = Ktg[t];
  if (tid < 64) {
    sq[tid] = sqw[(size_t)bh * 1024 + qbase + tid];
    cz[tid] = czw[(size_t)bh * 1024 + qbase + tid];
  }
  __syncthreads();

  const int wv = tid >> 6, l = tid & 63;
  const int l15 = l & 15, l4 = l >> 4;
  const int q = wv * 16 + l15;  // this lane's A-frag row
  const float s = sq[q], c = cz[q];
  f32x4 acc[4];
#pragma unroll
  for (int dt = 0; dt < 4; ++dt) acc[dt] = (f32x4){0.f, 0.f, 0.f, 0.f};

  const float* Vb = V + (size_t)bh * 65536;
  const int dV = tid & 63, kqV = tid >> 6;  // V-convert roles

  // ---- prologue: V loads for chunk 0 ----
  float vreg[2][8];
#pragma unroll
  for (int g = 0; g < 2; ++g) {
    const float* vs = Vb + (size_t)((kqV + g * 4) * 8) * 64 + dV;
#pragma unroll
    for (int i = 0; i < 8; ++i) vreg[g][i] = vs[i * 64];
  }

  for (int ch = 0; ch < 16; ++ch) {
    const int kc = ch * 64;
    const int buf = ch & 1;
    // ---- (a) E-phase in registers: exp -> bf16 hi/lo A-frags ----
    bf16x8 ahi[2], alo[2];
#pragma unroll
    for (int ks = 0; ks < 2; ++ks) {
      const int kb = kc + ks * 32 + l4 * 8;
      const float4 kv0 = *(const float4*)&Kts[kb];
      const float4 kv1 = *(const float4*)&Kts[kb + 4];
      float e[8];
      e[0] = __expf(fmaf(s, kv0.x, c));
      e[1] = __expf(fmaf(s, kv0.y, c));
      e[2] = __expf(fmaf(s, kv0.z, c));
      e[3] = __expf(fmaf(s, kv0.w, c));
      e[4] = __expf(fmaf(s, kv1.x, c));
      e[5] = __expf(fmaf(s, kv1.y, c));
      e[6] = __expf(fmaf(s, kv1.z, c));
      e[7] = __expf(fmaf(s, kv1.w, c));
      BF8 H, L;
#pragma unroll
      for (int i = 0; i < 8; ++i) {
        const __hip_bfloat16 hb = __float2bfloat16(e[i]);
        H.s[i] = __bfloat16_as_short(hb);
        L.s[i] =
            __bfloat16_as_short(__float2bfloat16(e[i] - __bfloat162float(hb)));
      }
      ahi[ks] = H.v;
      alo[ks] = L.v;
    }
    // ---- (b) convert V and commit to LDS B-frag layout ----
#pragma unroll
    for (int g = 0; g < 2; ++g) {
      const int ko = kqV + g * 4;
      BF8 H, L;
#pragma unroll
      for (int i = 0; i < 8; ++i) {
        const float f = vreg[g][i];
        const __hip_bfloat16 hb = __float2bfloat16(f);
        H.s[i] = __bfloat16_as_short(hb);
        L.s[i] =
            __bfloat16_as_short(__float2bfloat16(f - __bfloat162float(hb)));
      }
      *(bf16x8*)&Vhi[buf][(ko * 64 + dV) * 8] = H.v;
      *(bf16x8*)&Vlo[buf][(ko * 64 + dV) * 8] = L.v;
    }
    // ---- (c) LDS-only barrier ----
    lgkm_barrier();
    // ---- (d) prefetch V for chunk ch+1 (hides under PV) ----
    if (ch < 15) {
#pragma unroll
      for (int g = 0; g < 2; ++g) {
        const float* vs =
            Vb + (size_t)(kc + 64 + (kqV + g * 4) * 8) * 64 + dV;
#pragma unroll
        for (int i = 0; i < 8; ++i) vreg[g][i] = vs[i * 64];
      }
    }
    // ---- (e) PV: A from regs, B from LDS; 3 split MFMAs per (ks, dt) ----
#pragma unroll
    for (int ks = 0; ks < 2; ++ks) {
      const int ko = ks * 4 + l4;
#pragma unroll
      for (int dt = 0; dt < 4; ++dt) {
        const bf16x8 bhv =
            *(const bf16x8*)&Vhi[buf][(ko * 64 + dt * 16 + l15) * 8];
        const bf16x8 blv =
            *(const bf16x8*)&Vlo[buf][(ko * 64 + dt * 16 + l15) * 8];
        acc[dt] = __builtin_amdgcn_mfma_f32_16x16x32_bf16(ahi[ks], bhv,
                                                          acc[dt], 0, 0, 0);
        acc[dt] = __builtin_amdgcn_mfma_f32_16x16x32_bf16(ahi[ks], blv,
                                                          acc[dt], 0, 0, 0);
        acc[dt] = __builtin_amdgcn_mfma_f32_16x16x32_bf16(alo[ks], bhv,
                                                          acc[dt], 0, 0, 0);
      }
    }
  }
  // ---- epilogue: ctx write (D: row = wv*16 + 4*l4 + r, col = dt*16 + l15)
  float* cb = ctx + ((size_t)bh * 1024 + qbase + wv * 16 + l4 * 4) * 64 + l15;
#pragma unroll
  for (int dt = 0; dt < 4; ++dt)
#pragma unroll
    for (int rr = 0; rr < 4; ++rr) cb[(size_t)rr * 64 + dt * 16] = acc[dt][rr];
}

}  // namespace

extern "C" void kernel_launch(void* const* d_in, const int* in_sizes, int n_in,
                              void* d_out, int out_size, void* d_ws,
                              size_t ws_size, hipStream_t stream) {
  const float* Q = (const float*)d_in[0];
  const float* K = (const float*)d_in[1];
  const float* V = (const float*)d_in[2];
  const float* Wpq = (const float*)d_in[3];
  const float* Wbq = (const float*)d_in[4];
  const float* Wbk = (const float*)d_in[5];
  const float* bng = (const float*)d_in[6];
  const float* bnb = (const float*)d_in[7];
  // d_in[8] = attn_mask (all ones, unused)
  const float* cqw[4] = {(const float*)d_in[9], (const float*)d_in[13],
                         (const float*)d_in[17], (const float*)d_in[21]};
  const float* cqb[4] = {(const float*)d_in[10], (const float*)d_in[14],
                         (const float*)d_in[18], (const float*)d_in[22]};
  const float* ckw[4] = {(const float*)d_in[11], (const float*)d_in[15],
                         (const float*)d_in[19], (const float*)d_in[23]};
  const float* ckb[4] = {(const float*)d_in[12], (const float*)d_in[16],
                         (const float*)d_in[20], (const float*)d_in[24]};

  float* ws = (float*)d_ws;
  float* proj = ws + PROJ_OFF;
  float* conv = ws + CONV_OFF;
  float* psum = ws + PS_OFF;
  float* psumsq = ws + PSS_OFF;
  float* Qtp = ws + QT_OFF;
  float* Ktp = ws + KT_OFF;
  float* sqw = ws + SQ_OFF;  // aliases proj (dead after conv)
  float* czw = ws + CZ_OFF;  // aliases proj (dead after conv)
  float* ctx = (float*)d_out;
  float* attn = ctx + (size_t)8 * 8 * 1024 * 64;

  proj_kernel<<<512, 256, 0, stream>>>(Q, K, Wpq, proj);
  conv_kernel<<<256, 256, 0, stream>>>(
      proj, cqw[0], cqb[0], cqw[1], cqb[1], cqw[2], cqb[2], cqw[3], cqb[3],
      ckw[0], ckb[0], ckw[1], ckb[1], ckw[2], ckb[2], ckw[3], ckb[3], conv,
      psum, psumsq);
  sortmerge_kernel<<<128, 256, 0, stream>>>(conv, psum, psumsq, bng, bnb, Qtp,
                                            Ktp);
  attnw_kernel<<<2048, 256, 0, stream>>>(Qtp, Ktp, Wbq, Wbk, attn, sqw, czw);
  attnc_kernel<<<1024, 256, 0, stream>>>(V, Ktp, sqw, czw, ctx);
}

// Round 10
// 119.202 us; speedup vs baseline: 1.2001x; 1.2001x over previous
//
#include <hip/hip_runtime.h>
#include <hip/hip_bf16.h>
#include <math.h>

// ---------------- workspace layout (float offsets) ----------------
// proj  [2][8][8][1024]            @ 0        (131072)
// conv  [2][4][8][8][1024]         @ 131072   (524288)
// psum  [64][32]                   @ 655360   (2048)
// psumsq[64][32]                   @ 657408   (2048)
// Qt    [64][1024]                 @ 659456   (65536)
// Kt    [64][1024]                 @ 724992   (65536)
namespace {
constexpr int PROJ_OFF = 0;
constexpr int CONV_OFF = 131072;
constexpr int PS_OFF   = 655360;
constexpr int PSS_OFF  = 657408;
constexpr int QT_OFF   = 659456;
constexpr int KT_OFF   = 724992;

typedef short bf16x8 __attribute__((ext_vector_type(8)));
typedef float f32x4 __attribute__((ext_vector_type(4)));

union BF8 {
  bf16x8 v;
  short s[8];
};

// ---------------- kernel 1: projection q/k = X . W_pq (1 row/thread) -------
__global__ __launch_bounds__(256) void proj_kernel(
    const float* __restrict__ Q, const float* __restrict__ K,
    const float* __restrict__ Wpq, float* __restrict__ proj) {
  __shared__ float wsh[64];
  const int tid = threadIdx.x;
  if (tid < 64) wsh[tid] = Wpq[tid];
  __syncthreads();
  const int row = blockIdx.x * 256 + tid;  // 0..131071
  const float* src = (row < 65536) ? (Q + (size_t)row * 64)
                                   : (K + (size_t)(row - 65536) * 64);
  float acc = 0.f;
#pragma unroll
  for (int j = 0; j < 16; ++j) {
    const float4 v = *(const float4*)(src + j * 4);
    acc = fmaf(v.x, wsh[j * 4 + 0], acc);
    acc = fmaf(v.y, wsh[j * 4 + 1], acc);
    acc = fmaf(v.z, wsh[j * 4 + 2], acc);
    acc = fmaf(v.w, wsh[j * 4 + 3], acc);
  }
  proj[row] = acc;
}

// ---------------- kernel 2: conv1d + per-block BN partial sums --------------
template <int F>
__device__ void conv_body(const float* __restrict__ xs,
                          const float* __restrict__ wsm,
                          const float* __restrict__ bsm,
                          float* __restrict__ outp, int tid, int lq,
                          float accs[8]) {
  constexpr int pad = (F - 1) / 2;
#pragma unroll
  for (int j = 0; j < 8; ++j) {
    float acc = bsm[j];
#pragma unroll
    for (int c = 0; c < 8; ++c) {
      const float* xrow = &xs[c * 264 + tid + 4 - pad];
      const float* wrow = &wsm[(j * 8 + c) * F];
#pragma unroll
      for (int f = 0; f < F; ++f) acc = fmaf(xrow[f], wrow[f], acc);
    }
    outp[j * 1024 + lq * 256 + tid] = acc;
    accs[j] = acc;
  }
}

__global__ __launch_bounds__(256) void conv_kernel(
    const float* __restrict__ proj,
    const float* __restrict__ wq0, const float* __restrict__ bq0,
    const float* __restrict__ wq1, const float* __restrict__ bq1,
    const float* __restrict__ wq2, const float* __restrict__ bq2,
    const float* __restrict__ wq3, const float* __restrict__ bq3,
    const float* __restrict__ wk0, const float* __restrict__ bk0,
    const float* __restrict__ wk1, const float* __restrict__ bk1,
    const float* __restrict__ wk2, const float* __restrict__ bk2,
    const float* __restrict__ wk3, const float* __restrict__ bk3,
    float* __restrict__ conv, float* __restrict__ psum,
    float* __restrict__ psumsq) {
  __shared__ float xs[8 * 264];  // halo of 4 each side
  __shared__ float wsm[8 * 8 * 9];
  __shared__ float bsm[8];
  __shared__ float redS[8][4], redSS[8][4];
  const int tid = threadIdx.x;
  const int blk = blockIdx.x;  // 256 blocks: (path, filt, batch, lq)
  const int path = blk >> 7, fi = (blk >> 5) & 3, bb = (blk >> 2) & 7;
  const int lq = blk & 3;
  const int F = (0x9731 >> (fi * 4)) & 0xF;  // 1,3,7,9
  const float* wp;
  const float* bp;
  if (path == 0) {
    wp = fi == 0 ? wq0 : fi == 1 ? wq1 : fi == 2 ? wq2 : wq3;
    bp = fi == 0 ? bq0 : fi == 1 ? bq1 : fi == 2 ? bq2 : bq3;
  } else {
    wp = fi == 0 ? wk0 : fi == 1 ? wk1 : fi == 2 ? wk2 : wk3;
    bp = fi == 0 ? bk0 : fi == 1 ? bk1 : fi == 2 ? bk2 : bk3;
  }
  const float* pb = proj + path * 65536 + bb * 8192;
  for (int e = tid; e < 8 * 264; e += 256) {
    const int c = e / 264, pos = e - c * 264;
    const int gl = lq * 256 + pos - 4;
    xs[e] = (gl >= 0 && gl < 1024) ? pb[c * 1024 + gl] : 0.f;
  }
  for (int e = tid; e < 64 * F; e += 256) wsm[e] = wp[e];
  if (tid < 8) bsm[tid] = bp[tid];
  __syncthreads();
  float* outp = conv + ((size_t)(path * 4 + fi) * 8 + bb) * 8192;
  float accs[8];
  if (fi == 0)
    conv_body<1>(xs, wsm, bsm, outp, tid, lq, accs);
  else if (fi == 1)
    conv_body<3>(xs, wsm, bsm, outp, tid, lq, accs);
  else if (fi == 2)
    conv_body<7>(xs, wsm, bsm, outp, tid, lq, accs);
  else
    conv_body<9>(xs, wsm, bsm, outp, tid, lq, accs);
  // block reduction of per-channel sum / sumsq (deterministic, no atomics)
  const int lane = tid & 63, wv = tid >> 6;
#pragma unroll
  for (int j = 0; j < 8; ++j) {
    float sv = accs[j], qv = accs[j] * accs[j];
#pragma unroll
    for (int mm = 32; mm >= 1; mm >>= 1) {
      sv += __shfl_xor(sv, mm, 64);
      qv += __shfl_xor(qv, mm, 64);
    }
    if (lane == 0) {
      redS[j][wv] = sv;
      redSS[j][wv] = qv;
    }
  }
  __syncthreads();
  if (tid < 16) {
    const int j = tid & 7;
    const bool wantss = tid >= 8;
    const float* rr = wantss ? &redSS[j][0] : &redS[j][0];
    const float tot = rr[0] + rr[1] + rr[2] + rr[3];
    float* dst = wantss ? psumsq : psum;
    dst[((path * 4 + fi) * 8 + j) * 32 + bb * 4 + lq] = tot;
  }
}

__device__ inline float bn_elu(float v, float mean, float rstd, float g,
                               float be) {
  const float x = (v - mean) * rstd * g + be;
  return x > 0.f ? x : expm1f(x);
}

// ============ wave-synchronous bitonic sort (16 elems/lane, no barriers) ====
// g = lane*16 + e; descending; up==true => keep larger at lower index.
__device__ inline void cswap(float& a, float& b, bool up) {
  const float mx = fmaxf(a, b), mn = fminf(a, b);
  a = up ? mx : mn;
  b = up ? mn : mx;
}

__device__ inline void wsort1024(float v[16], int lane) {
#pragma unroll
  for (int k = 2; k <= 1024; k <<= 1) {
    // cross-lane passes: j = k/2 .. 16  (shfl distance j/16)
#pragma unroll
    for (int j = 512; j >= 16; j >>= 1) {
      if (j <= (k >> 1)) {
        const int lj = j >> 4;
        const bool up = ((lane & (k >> 4)) == 0);  // k>=32 here
        const bool keep = (up == ((lane & lj) == 0));
#pragma unroll
        for (int e = 0; e < 16; ++e) {
          const float p = __shfl_xor(v[e], lj, 64);
          v[e] = keep ? fmaxf(v[e], p) : fminf(v[e], p);
        }
      }
    }
    // in-lane passes: j = min(8, k/2) .. 1
#pragma unroll
    for (int j = 8; j >= 1; j >>= 1) {
      if (j <= (k >> 1)) {
#pragma unroll
        for (int e = 0; e < 16; ++e) {
          if ((e & j) == 0) {
            bool up;
            if (k >= 32)
              up = ((lane & (k >> 4)) == 0);
            else if (k == 16)
              up = ((lane & 1) == 0);
            else
              up = ((e & k) == 0);
            cswap(v[e], v[e ^ j], up);
          }
        }
      }
    }
  }
}

// bitonic 1024-seq -> descending sorted, wave-local (up = true everywhere)
__device__ inline void wmerge1024(float v[16], int lane) {
#pragma unroll
  for (int lj = 32; lj >= 1; lj >>= 1) {
    const bool keep = ((lane & lj) == 0);
#pragma unroll
    for (int e = 0; e < 16; ++e) {
      const float p = __shfl_xor(v[e], lj, 64);
      v[e] = keep ? fmaxf(v[e], p) : fminf(v[e], p);
    }
  }
#pragma unroll
  for (int j = 8; j >= 1; j >>= 1)
#pragma unroll
    for (int e = 0; e < 16; ++e)
      if ((e & j) == 0) cswap(v[e], v[e ^ j], true);
}

// ---------------- kernel 3: stats-finalize + wave-parallel sorts + merge ----
// grid 80: blk<64 -> Q row (4 waves sort 4 chunks concurrently, 2-barrier
// merge to top-1024); blk>=64 -> 4 K rows, one per wave (no barriers).
__global__ __launch_bounds__(256) void sortmerge2_kernel(
    const float* __restrict__ conv, const float* __restrict__ psum,
    const float* __restrict__ psumsq, const float* __restrict__ bng,
    const float* __restrict__ bnb, float* __restrict__ Qt,
    float* __restrict__ Kt) {
  __shared__ float s1[1024];
  __shared__ float s2[1024];
  const int tid = threadIdx.x, blk = blockIdx.x;
  const int wv = tid >> 6, l = tid & 63;
  float v[16];
  if (blk < 64) {
    // ---------------- Q row: wave wv sorts chunk jc = wv ----------------
    const int row = blk;
    const int hp = row & 7, fi = row >> 4;
    const int bb = ((row >> 3) & 1) * 4 + (hp >> 1);
    const int hh = (hp & 1) * 4 + wv;
    const int ch = fi * 8 + hh;  // Q path channel (psum index)
    float sval = 0.f;
    if (l < 2) {
      const float* src = (l == 0) ? psum : psumsq;
#pragma unroll
      for (int i = 0; i < 32; ++i) sval += src[ch * 32 + i];
    }
    const float mean = __shfl(sval, 0, 64) * (1.f / 8192.f);
    const float msq = __shfl(sval, 1, 64) * (1.f / 8192.f);
    const float rstd = rsqrtf(fmaxf(msq - mean * mean, 0.f) + 1e-5f);
    const float g = bng[hh], be = bnb[hh];
    const float* base = conv + (size_t)(fi * 8 + bb) * 8192 + hh * 1024;
#pragma unroll
    for (int j = 0; j < 4; ++j) {
      const float4 x = *(const float4*)&base[l * 16 + j * 4];
      v[j * 4 + 0] = bn_elu(x.x, mean, rstd, g, be);
      v[j * 4 + 1] = bn_elu(x.y, mean, rstd, g, be);
      v[j * 4 + 2] = bn_elu(x.z, mean, rstd, g, be);
      v[j * 4 + 3] = bn_elu(x.w, mean, rstd, g, be);
    }
    wsort1024(v, l);
    // merge: top-1024 of the 4 sorted chunks
    if (wv == 1)
#pragma unroll
      for (int e = 0; e < 16; ++e) s1[l * 16 + e] = v[e];
    if (wv == 3)
#pragma unroll
      for (int e = 0; e < 16; ++e) s2[l * 16 + e] = v[e];
    __syncthreads();
    if (wv == 0) {
#pragma unroll
      for (int e = 0; e < 16; ++e)
        v[e] = fmaxf(v[e], s1[1023 - (l * 16 + e)]);
      wmerge1024(v, l);  // a = top(c0 U c1)
    } else if (wv == 2) {
#pragma unroll
      for (int e = 0; e < 16; ++e)
        v[e] = fmaxf(v[e], s2[1023 - (l * 16 + e)]);
      wmerge1024(v, l);  // b = top(c2 U c3)
#pragma unroll
      for (int e = 0; e < 16; ++e) s2[l * 16 + e] = v[e];
    }
    __syncthreads();
    if (wv == 0) {
#pragma unroll
      for (int e = 0; e < 16; ++e)
        v[e] = fmaxf(v[e], s2[1023 - (l * 16 + e)]);
      wmerge1024(v, l);  // final top-1024 sorted desc
      float* qd = Qt + (size_t)row * 1024 + l * 16;
#pragma unroll
      for (int j = 0; j < 4; ++j)
        *(float4*)&qd[j * 4] =
            make_float4(v[j * 4], v[j * 4 + 1], v[j * 4 + 2], v[j * 4 + 3]);
    }
  } else {
    // ---------------- K rows: wave wv handles row (blk-64)*4 + wv ----------
    const int row = (blk - 64) * 4 + wv;
    const int hp = row & 7, fi = row >> 4;
    const int bb = ((row >> 3) & 1) * 4 + (hp >> 1);
    const int chk = 32 + fi * 8 + (hp & 1) * 4;  // K path channel base
    float sval = 0.f;
    if (l < 8) {
      const float* src = (l < 4) ? psum : psumsq;
      const int ch = chk + (l & 3);
#pragma unroll
      for (int i = 0; i < 32; ++i) sval += src[ch * 32 + i];
    }
    float cm[4], cr[4];
#pragma unroll
    for (int j = 0; j < 4; ++j) {
      const float mean = __shfl(sval, j, 64) * (1.f / 8192.f);
      const float msq = __shfl(sval, j + 4, 64) * (1.f / 8192.f);
      cm[j] = mean;
      cr[j] = rsqrtf(fmaxf(msq - mean * mean, 0.f) + 1e-5f);
    }
#pragma unroll
    for (int e = 0; e < 16; ++e) v[e] = 0.f;
#pragma unroll
    for (int j = 0; j < 4; ++j) {
      const int hh = (hp & 1) * 4 + j;
      const float g = bng[hh], be = bnb[hh];
      const float* base =
          conv + (size_t)(4 + fi) * 64 * 1024 + (size_t)bb * 8192 + hh * 1024;
#pragma unroll
      for (int jj = 0; jj < 4; ++jj) {
        const float4 x = *(const float4*)&base[l * 16 + jj * 4];
        v[jj * 4 + 0] += bn_elu(x.x, cm[j], cr[j], g, be);
        v[jj * 4 + 1] += bn_elu(x.y, cm[j], cr[j], g, be);
        v[jj * 4 + 2] += bn_elu(x.z, cm[j], cr[j], g, be);
        v[jj * 4 + 3] += bn_elu(x.w, cm[j], cr[j], g, be);
      }
    }
#pragma unroll
    for (int e = 0; e < 16; ++e) v[e] *= 0.25f;
    wsort1024(v, l);
    float* kd = Kt + (size_t)row * 1024 + l * 16;
#pragma unroll
    for (int j = 0; j < 4; ++j)
      *(float4*)&kd[j * 4] =
          make_float4(v[j * 4], v[j * 4 + 1], v[j * 4 + 2], v[j * 4 + 3]);
  }
}

// ---------------- kernel 4: softmax + attn write + MFMA PV (R6 attn5) ------
// grid 1024 = 64 bh x 16 q-tiles of 64 rows; 256 threads (4 waves).
__global__ __launch_bounds__(256, 4) void attn5_kernel(
    const float* __restrict__ V, const float* __restrict__ Qt,
    const float* __restrict__ Kt, const float* __restrict__ Wbq,
    const float* __restrict__ Wbk, float* __restrict__ ctx,
    float* __restrict__ attn) {
  __shared__ float Kts[1024];
  __shared__ float sq[64], mq[64], rz[64];
  __shared__ short Vhi[2][8 * 64 * 8];  // [buf][ko][d][8k] bf16
  __shared__ short Vlo[2][8 * 64 * 8];
  const int tid = threadIdx.x;
  const int b = blockIdx.x;
  // XCD swizzle: all 16 q-tiles of one bh on one XCD (1024 % 8 == 0).
  const int bh = ((b & 7) << 3) | ((b >> 3) & 7);
  const int qt = b >> 6;  // 0..15
  const int qbase = qt * 64;
  const int lane0 = tid & 63;
  float cval;
  {
    float d = Wbq[lane0] * Wbk[lane0];
#pragma unroll
    for (int mm = 32; mm >= 1; mm >>= 1) d += __shfl_xor(d, mm, 64);
    cval = d * 0.125f;  // / sqrt(64)
  }
  const float* Ktg = Kt + (size_t)bh * 1024;
  for (int t = tid; t < 1024; t += 256) Kts[t] = Ktg[t];
  const float kHi = Ktg[0], kLo = Ktg[1023];  // sorted descending
  if (tid < 64) {
    const float s = cval * Qt[(size_t)bh * 1024 + qbase + tid];
    sq[tid] = s;
    mq[tid] = fmaxf(s * kHi, s * kLo);
  }
  __syncthreads();
  {  // Z pass: 4 threads per q-row
    const int row = tid >> 2, qtr = tid & 3;
    const float s = sq[row], m = mq[row];
    float z = 0.f;
    const int k0 = qtr * 256;
    for (int k = 0; k < 256; ++k) z += __expf(fmaf(s, Kts[k0 + k], -m));
    z += __shfl_xor(z, 1, 64);
    z += __shfl_xor(z, 2, 64);
    if (qtr == 0) rz[row] = 1.f / z;
  }
  __syncthreads();

  const int wv = tid >> 6, l = tid & 63;
  const int l15 = l & 15, l4 = l >> 4;
  const int q = wv * 16 + l15;  // this lane's A-frag row
  const float s = sq[q], m = mq[q], r = rz[q];
  f32x4 acc[4];
#pragma unroll
  for (int dt = 0; dt < 4; ++dt) acc[dt] = (f32x4){0.f, 0.f, 0.f, 0.f};

  const float* Vb = V + (size_t)bh * 65536;
  float* arow = attn + ((size_t)bh << 20) + (size_t)qbase * 1024;
  const int dV = tid & 63, kqV = tid >> 6;  // V-convert roles

  for (int ch = 0; ch < 16; ++ch) {
    const int kc = ch * 64;
    const int buf = ch & 1;
    // ---- (a) issue V global loads early (latency hides under E-phase) ----
    float vreg[2][8];
#pragma unroll
    for (int g = 0; g < 2; ++g) {
      const int ko = kqV + g * 4;
      const float* vs = Vb + (size_t)(kc + ko * 8) * 64 + dV;
#pragma unroll
      for (int i = 0; i < 8; ++i) vreg[g][i] = vs[i * 64];
    }
    // ---- (b) E-phase in registers: exp -> attn write -> bf16 hi/lo ----
    bf16x8 ahi[2], alo[2];
#pragma unroll
    for (int ks = 0; ks < 2; ++ks) {
      const int kb = kc + ks * 32 + l4 * 8;
      const float4 kv0 = *(const float4*)&Kts[kb];
      const float4 kv1 = *(const float4*)&Kts[kb + 4];
      float e[8];
      e[0] = __expf(fmaf(s, kv0.x, -m)) * r;
      e[1] = __expf(fmaf(s, kv0.y, -m)) * r;
      e[2] = __expf(fmaf(s, kv0.z, -m)) * r;
      e[3] = __expf(fmaf(s, kv0.w, -m)) * r;
      e[4] = __expf(fmaf(s, kv1.x, -m)) * r;
      e[5] = __expf(fmaf(s, kv1.y, -m)) * r;
      e[6] = __expf(fmaf(s, kv1.z, -m)) * r;
      e[7] = __expf(fmaf(s, kv1.w, -m)) * r;
      float* ag = arow + (size_t)q * 1024 + kb;
      *(float4*)ag = make_float4(e[0], e[1], e[2], e[3]);
      *(float4*)(ag + 4) = make_float4(e[4], e[5], e[6], e[7]);
      BF8 H, L;
#pragma unroll
      for (int i = 0; i < 8; ++i) {
        const __hip_bfloat16 hb = __float2bfloat16(e[i]);
        H.s[i] = __bfloat16_as_short(hb);
        L.s[i] =
            __bfloat16_as_short(__float2bfloat16(e[i] - __bfloat162float(hb)));
      }
      ahi[ks] = H.v;
      alo[ks] = L.v;
    }
    // ---- (c) convert V and commit to LDS B-frag layout ----
#pragma unroll
    for (int g = 0; g < 2; ++g) {
      const int ko = kqV + g * 4;
      BF8 H, L;
#pragma unroll
      for (int i = 0; i < 8; ++i) {
        const float f = vreg[g][i];
        const __hip_bfloat16 hb = __float2bfloat16(f);
        H.s[i] = __bfloat16_as_short(hb);
        L.s[i] =
            __bfloat16_as_short(__float2bfloat16(f - __bfloat162float(hb)));
      }
      *(bf16x8*)&Vhi[buf][(ko * 64 + dV) * 8] = H.v;
      *(bf16x8*)&Vlo[buf][(ko * 64 + dV) * 8] = L.v;
    }
    __syncthreads();
    // ---- (d) PV: A from regs, B from LDS; 3 split MFMAs per (ks, dt) ----
#pragma unroll
    for (int ks = 0; ks < 2; ++ks) {
      const int ko = ks * 4 + l4;
#pragma unroll
      for (int dt = 0; dt < 4; ++dt) {
        const bf16x8 bhv =
            *(const bf16x8*)&Vhi[buf][(ko * 64 + dt * 16 + l15) * 8];
        const bf16x8 blv =
            *(const bf16x8*)&Vlo[buf][(ko * 64 + dt * 16 + l15) * 8];
        acc[dt] = __builtin_amdgcn_mfma_f32_16x16x32_bf16(ahi[ks], bhv,
                                                          acc[dt], 0, 0, 0);
        acc[dt] = __builtin_amdgcn_mfma_f32_16x16x32_bf16(ahi[ks], blv,
                                                          acc[dt], 0, 0, 0);
        acc[dt] = __builtin_amdgcn_mfma_f32_16x16x32_bf16(alo[ks], bhv,
                                                          acc[dt], 0, 0, 0);
      }
    }
  }
  // ---- epilogue: ctx write (D: row = wv*16 + 4*l4 + r, col = dt*16 + l15)
  float* cb = ctx + ((size_t)bh * 1024 + qbase + wv * 16 + l4 * 4) * 64 + l15;
#pragma unroll
  for (int dt = 0; dt < 4; ++dt)
#pragma unroll
    for (int rr = 0; rr < 4; ++rr) cb[(size_t)rr * 64 + dt * 16] = acc[dt][rr];
}

}  // namespace

extern "C" void kernel_launch(void* const* d_in, const int* in_sizes, int n_in,
                              void* d_out, int out_size, void* d_ws,
                              size_t ws_size, hipStream_t stream) {
  const float* Q = (const float*)d_in[0];
  const float* K = (const float*)d_in[1];
  const float* V = (const float*)d_in[2];
  const float* Wpq = (const float*)d_in[3];
  const float* Wbq = (const float*)d_in[4];
  const float* Wbk = (const float*)d_in[5];
  const float* bng = (const float*)d_in[6];
  const float* bnb = (const float*)d_in[7];
  // d_in[8] = attn_mask (all ones, unused)
  const float* cqw[4] = {(const float*)d_in[9], (const float*)d_in[13],
                         (const float*)d_in[17], (const float*)d_in[21]};
  const float* cqb[4] = {(const float*)d_in[10], (const float*)d_in[14],
                         (const float*)d_in[18], (const float*)d_in[22]};
  const float* ckw[4] = {(const float*)d_in[11], (const float*)d_in[15],
                         (const float*)d_in[19], (const float*)d_in[23]};
  const float* ckb[4] = {(const float*)d_in[12], (const float*)d_in[16],
                         (const float*)d_in[20], (const float*)d_in[24]};

  float* ws = (float*)d_ws;
  float* proj = ws + PROJ_OFF;
  float* conv = ws + CONV_OFF;
  float* psum = ws + PS_OFF;
  float* psumsq = ws + PSS_OFF;
  float* Qtp = ws + QT_OFF;
  float* Ktp = ws + KT_OFF;
  float* ctx = (float*)d_out;
  float* attn = ctx + (size_t)8 * 8 * 1024 * 64;

  proj_kernel<<<512, 256, 0, stream>>>(Q, K, Wpq, proj);
  conv_kernel<<<256, 256, 0, stream>>>(
      proj, cqw[0], cqb[0], cqw[1], cqb[1], cqw[2], cqb[2], cqw[3], cqb[3],
      ckw[0], ckb[0], ckw[1], ckb[1], ckw[2], ckb[2], ckw[3], ckb[3], conv,
      psum, psumsq);
  sortmerge2_kernel<<<80, 256, 0, stream>>>(conv, psum, psumsq, bng, bnb, Qtp,
                                            Ktp);
  attn5_kernel<<<1024, 256, 0, stream>>>(V, Qtp, Ktp, Wbq, Wbk, ctx, attn);
}